// Round 3
// baseline (74.967 us; speedup 1.0000x reference)
//
#include <hip/hip_runtime.h>
#include <math.h>

#define LSEQ 4096
#define NK 512
#define NB 16
#define SEG_G 16

__global__ void build_iperm_kernel(const int* __restrict__ perm, int* __restrict__ iperm) {
    int j = threadIdx.x + blockIdx.x * blockDim.x;
    if (j < NK) iperm[perm[j]] = j;
}

template <int KS>
__device__ __forceinline__ void rocket_block(
    const float* __restrict__ xr,     // x row for batch b
    const float* __restrict__ w,      // [n, KS]
    const float* __restrict__ bias,   // [n]
    const int*   __restrict__ off,    // [n, KS]
    const int*   __restrict__ lout,   // [n]
    const int*   __restrict__ iperm,  // [NK]
    int P, int base, int li, int b,
    float* __restrict__ out)
{
    const int tid = threadIdx.x;

    float wk[KS];
#pragma unroll
    for (int k = 0; k < KS; ++k) wk[k] = w[li * KS + k];

    const int o0  = off[li * KS + 0];      // = P - pad
    const int o1  = off[li * KS + 1];      // = P - pad + d
    const int d   = o1 - o0;               // dilation (>=1)
    const int pad = P - o0;                // total pad (>=0)
    const float bi = bias[li];
    const int   Lo = lout[li];

    // interior: all taps idx = t - pad + k*d in [0, LSEQ)
    int t_lo = min(pad, Lo);                               // max(0,pad) clamped
    int t_hi = min(Lo, LSEQ - (KS - 1) * d + pad);
    if (t_hi < t_lo) t_hi = t_lo;

    float mx  = -INFINITY;
    int   cnt = 0;

    // ---- left edge [0, t_lo): bounds-checked taps ----
    for (int t = tid; t < t_lo; t += 256) {
        float y = bi;
        int idx = t - pad;
#pragma unroll
        for (int k = 0; k < KS; ++k) {
            float xv = ((unsigned)idx < (unsigned)LSEQ) ? xr[idx] : 0.0f;
            y = fmaf(wk[k], xv, y);
            idx += d;
        }
        mx = fmaxf(mx, y);
        cnt += (y > 0.0f) ? 1 : 0;
    }

    // ---- interior [t_lo, t_hi): sliding-window chains, no bounds checks ----
    const int Ni = t_hi - t_lo;
    if (Ni > 0) {
        const unsigned ud   = (unsigned)d;
        const int Mmax      = (Ni + d - 1) / d;            // max outputs per chain
        const int Jmax      = (Mmax + SEG_G - 1) / SEG_G;  // segments per chain
        const int nseg      = d * Jmax;
        for (int s = tid; s < nseg; s += 256) {
            const int j  = (int)((unsigned)s / ud);
            const int r  = s - j * d;
            const int t0 = t_lo + r + j * (SEG_G * d);
            if (t0 >= t_hi) continue;
            const float* __restrict__ xp = xr + (t0 - pad);
            float W[KS];
            int aa = 0;
#pragma unroll
            for (int k = 0; k < KS - 1; ++k) { W[k] = xp[aa]; aa += d; }
            const int rem = t_hi - t0;          // remaining t-range in chain
            int a   = (KS - 1) * d;             // tap (KS-1) byte-index (in elems)
            const int lim = rem + a;            // a < lim  <=>  g*d < rem
#pragma unroll
            for (int g = 0; g < SEG_G; ++g) {
                if (a < lim) {
                    W[KS - 1] = xp[a];
                    float y = bi;
#pragma unroll
                    for (int k = 0; k < KS; ++k) y = fmaf(wk[k], W[k], y);
                    mx = fmaxf(mx, y);
                    cnt += (y > 0.0f) ? 1 : 0;
#pragma unroll
                    for (int k = 0; k < KS - 1; ++k) W[k] = W[k + 1];
                }
                a += d;
            }
        }
    }

    // ---- right edge [t_hi, Lo): bounds-checked taps ----
    for (int t = t_hi + tid; t < Lo; t += 256) {
        float y = bi;
        int idx = t - pad;
#pragma unroll
        for (int k = 0; k < KS; ++k) {
            float xv = ((unsigned)idx < (unsigned)LSEQ) ? xr[idx] : 0.0f;
            y = fmaf(wk[k], xv, y);
            idx += d;
        }
        mx = fmaxf(mx, y);
        cnt += (y > 0.0f) ? 1 : 0;
    }

    // ---- wave64 + block reduction ----
#pragma unroll
    for (int o = 32; o > 0; o >>= 1) {
        mx = fmaxf(mx, __shfl_down(mx, o, 64));
        cnt += __shfl_down(cnt, o, 64);
    }

    __shared__ float smx[4];
    __shared__ int   scnt[4];
    const int wid = tid >> 6;
    if ((tid & 63) == 0) { smx[wid] = mx; scnt[wid] = cnt; }
    __syncthreads();

    if (tid == 0) {
        float m = smx[0];
        int   c = scnt[0];
#pragma unroll
        for (int i = 1; i < 4; ++i) { m = fmaxf(m, smx[i]); c += scnt[i]; }
        const int j = iperm[base + li];
        out[b * (2 * NK) + 2 * j]     = m;
        out[b * (2 * NK) + 2 * j + 1] = (float)c / (float)Lo;
    }
}

__global__ __launch_bounds__(256) void rocket_fused_kernel(
    const float* __restrict__ x,
    const float* __restrict__ w0, const float* __restrict__ b0,
    const int* __restrict__ off0, const int* __restrict__ l0,
    const float* __restrict__ w1, const float* __restrict__ b1,
    const int* __restrict__ off1, const int* __restrict__ l1,
    const float* __restrict__ w2, const float* __restrict__ b2,
    const int* __restrict__ off2, const int* __restrict__ l2,
    const int* __restrict__ iperm, const int* __restrict__ Pp,
    int n0, int n01,
    float* __restrict__ out)
{
    const int gid = blockIdx.x;       // 0..511 global kernel index (group-ordered)
    const int b   = blockIdx.y;
    const int P   = *Pp;
    const float* xr = x + (size_t)b * LSEQ;

    if (gid < n0) {
        rocket_block<7>(xr, w0, b0, off0, l0, iperm, P, 0, gid, b, out);
    } else if (gid < n01) {
        rocket_block<9>(xr, w1, b1, off1, l1, iperm, P, n0, gid - n0, b, out);
    } else {
        rocket_block<11>(xr, w2, b2, off2, l2, iperm, P, n01, gid - n01, b, out);
    }
}

extern "C" void kernel_launch(void* const* d_in, const int* in_sizes, int n_in,
                              void* d_out, int out_size, void* d_ws, size_t ws_size,
                              hipStream_t stream) {
    const float* x    = (const float*)d_in[0];
    const int*   perm = (const int*)d_in[1];
    const int*   Pp   = (const int*)d_in[2];
    const float* w0   = (const float*)d_in[3];
    const float* b0   = (const float*)d_in[4];
    const int*   off0 = (const int*)d_in[5];
    const int*   l0   = (const int*)d_in[6];
    const float* w1   = (const float*)d_in[7];
    const float* b1   = (const float*)d_in[8];
    const int*   off1 = (const int*)d_in[9];
    const int*   l1   = (const int*)d_in[10];
    const float* w2   = (const float*)d_in[11];
    const float* b2   = (const float*)d_in[12];
    const int*   off2 = (const int*)d_in[13];
    const int*   l2   = (const int*)d_in[14];

    const int n0 = in_sizes[4];
    const int n1 = in_sizes[8];

    float* out = (float*)d_out;
    int* iperm = (int*)d_ws;

    build_iperm_kernel<<<1, NK, 0, stream>>>(perm, iperm);

    rocket_fused_kernel<<<dim3(NK, NB), 256, 0, stream>>>(
        x, w0, b0, off0, l0, w1, b1, off1, l1, w2, b2, off2, l2,
        iperm, Pp, n0, n0 + n1, out);
}